// Round 1
// baseline (163.534 us; speedup 1.0000x reference)
//
#include <hip/hip_runtime.h>
#include <hip/hip_bf16.h>

#define L_    4096
#define DIN   512
#define DOUT  256
#define NH    4
#define HD    64
#define JW    128                      // L_/32 j-words per row

typedef unsigned short u16;
typedef __attribute__((ext_vector_type(8))) short short8;   // 8 x bf16
typedef __attribute__((ext_vector_type(4))) float floatx4;  // MFMA C/D frag

__device__ __forceinline__ float bf2f(u16 u) {
  union { unsigned u32; float f; } v; v.u32 = ((unsigned)u) << 16; return v.f;
}
__device__ __forceinline__ u16 f2bf(float f) {  // RNE
  union { float f; unsigned u; } v; v.f = f;
  unsigned r = v.u + 0x7fff + ((v.u >> 16) & 1);
  return (u16)(r >> 16);
}
__device__ __forceinline__ unsigned cvt2(float a, float b) {  // HW pack fp32x2->bf16x2
  __hip_bfloat162 v = __float22bfloat162_rn(make_float2(a, b));
  return *reinterpret_cast<unsigned*>(&v);
}
__device__ __forceinline__ short8 pack8(const float* __restrict__ p) {
  float4 a = *(const float4*)p, b = *(const float4*)(p + 4);
  union { unsigned u[4]; short8 s; } r;
  r.u[0] = cvt2(a.x, a.y); r.u[1] = cvt2(a.z, a.w);
  r.u[2] = cvt2(b.x, b.y); r.u[3] = cvt2(b.z, b.w);
  return r.s;
}

// C/D map discovery (r10-verified contract); layout-map-free probes.
__device__ __forceinline__ void mfma_cdmap(int lane, int* rowm, int* colm) {
  const int c0 = lane & 15;
  union { u16 u[8]; short8 s; } a1, b1, a2, b2;
  const u16 one = f2bf(1.f), cid = f2bf((float)c0);
  #pragma unroll
  for (int j = 0; j < 8; ++j) { a1.u[j] = cid; b1.u[j] = one; a2.u[j] = one; b2.u[j] = cid; }
  floatx4 z = {0.f, 0.f, 0.f, 0.f};
  floatx4 dr = __builtin_amdgcn_mfma_f32_16x16x32_bf16(a1.s, b1.s, z, 0, 0, 0);
  floatx4 dc = __builtin_amdgcn_mfma_f32_16x16x32_bf16(a2.s, b2.s, z, 0, 0, 0);
  #pragma unroll
  for (int r = 0; r < 4; ++r) {
    rowm[r] = (int)(dr[r] * 0.03125f + 0.5f);
    colm[r] = (int)(dc[r] * 0.03125f + 0.5f);
  }
}

// ---------------------------------------------------------------------------
// k0b: W (fp32 256x512) -> Wf (bf16, k1-fragment chunk order, 256 KB in d_out).
// ---------------------------------------------------------------------------
__global__ __launch_bounds__(256) void k0b_wf(const float* __restrict__ W,
                                              u16* __restrict__ Wf) {
  const int g = blockIdx.x * 256 + threadIdx.x;   // 4096 threads
  const int col = g >> 4, kblock = g & 15;
  const int cg = col >> 6, nt = (col >> 4) & 3, c0 = col & 15;
  const float* src = W + (size_t)col * DIN + kblock * 32;
  u16* dst = Wf + ((size_t)(cg * 4 + nt) * 16 + kblock) * 512 + c0 * 8;
  #pragma unroll
  for (int q = 0; q < 4; ++q) {
    short8 v = pack8(src + q * 8);
    *(short8*)(dst + q * 128) = v;     // (q*16+c0)*8 = q*128 + c0*8
  }
}

// ---------------------------------------------------------------------------
// K1: Wh = h @ W.T. Block 1024 = 16 waves (cg = wv&3, kc = wv>>2).
// (r13-verified) h staged to LDS bf16; W coalesced from Wf; phased 2-plane
// reduction. Outputs s1 fp32 + bd=(exp(s2),exp(.2*s2)) float2 + WhTf (bf16).
// ---------------------------------------------------------------------------
__global__ __launch_bounds__(1024) void k1_wh(
    const float* __restrict__ h, const u16* __restrict__ Wf,
    const float* __restrict__ attn,
    u16* __restrict__ WhTf, float* __restrict__ s1g, float2* __restrict__ bdg)
{
  const int i0 = blockIdx.x * 16;
  const int t = threadIdx.x;
  const int wv = t >> 6, lane = t & 63, q = lane >> 4, c0 = lane & 15;
  const int cg = wv & 3, kc = wv >> 2;
  int rowm[4], colm[4];
  mfma_cdmap(lane, rowm, colm);

  __shared__ u16  hT[16][DIN + 8];
  __shared__ float pA[16][DOUT + 8];
  __shared__ float pB[16][DOUT + 8];
  __shared__ float attnL[NH * 128];

  if (t < 512) attnL[t] = attn[t];
  {  // stage h-tile coalesced
    const int row = t >> 6, c8 = (t & 63) * 8;
    const float* hp = h + (size_t)(i0 + row) * DIN + c8;
    float4 a = *(const float4*)hp;
    float4 b = *(const float4*)(hp + 4);
    union { unsigned u[4]; int4 v; } pk;
    pk.u[0] = cvt2(a.x, a.y); pk.u[1] = cvt2(a.z, a.w);
    pk.u[2] = cvt2(b.x, b.y); pk.u[3] = cvt2(b.z, b.w);
    *(int4*)&hT[row][c8] = pk.v;
  }
  __syncthreads();

  floatx4 acc[4] = {};
  #pragma unroll
  for (int ktl = 0; ktl < 4; ++ktl) {
    const int kb = kc * 128 + ktl * 32 + q * 8;
    short8 af = *(const short8*)&hT[c0][kb];        // A[m=c0][k]
    #pragma unroll
    for (int nt = 0; nt < 4; ++nt) {
      short8 bf = *(const short8*)(Wf + ((size_t)(cg * 4 + nt) * 16 + kc * 4 + ktl) * 512 + lane * 8);
      acc[nt] = __builtin_amdgcn_mfma_f32_16x16x32_bf16(af, bf, acc[nt], 0, 0, 0);
    }
  }

  auto writeT = [&](float (*P)[DOUT + 8]) {
    #pragma unroll
    for (int nt = 0; nt < 4; ++nt)
      #pragma unroll
      for (int r = 0; r < 4; ++r)
        P[rowm[r]][cg * 64 + nt * 16 + colm[r]] = acc[nt][r];
  };
  auto addB2A = [&]() {
    const int row = t >> 6, c4 = (t & 63) * 4;
    float4* a = (float4*)&pA[row][c4];
    float4 bv = *(float4*)&pB[row][c4];
    float4 av = *a;
    av.x += bv.x; av.y += bv.y; av.z += bv.z; av.w += bv.w;
    *a = av;
  };

  if (kc == 0) writeT(pA);
  if (kc == 1) writeT(pB);
  __syncthreads();
  addB2A();
  __syncthreads();
  if (kc == 2) writeT(pB);
  __syncthreads();
  addB2A();
  __syncthreads();
  if (kc == 3) writeT(pB);
  __syncthreads();
  addB2A();
  __syncthreads();

  if (t < 64) {  // s1 + factored-exp pair for s2
    const int r = t & 15, hh = t >> 4;
    float s1 = 0.f, s2 = 0.f;
    for (int d = 0; d < HD; ++d) {
      float v = pA[r][hh * 64 + d];
      s1 += v * attnL[hh * 128 + d];
      s2 += v * attnL[hh * 128 + 64 + d];
    }
    s1g[hh * L_ + i0 + r] = s1;
    bdg[hh * L_ + i0 + r] = make_float2(__expf(s2), __expf(0.2f * s2));
  }

  if (t < 256) {  // WhTf store: thread t = d; two 16B writes
    const int d = t;
    const int hd = d >> 6, nt = (d >> 4) & 3, dc0 = d & 15;
    const int jblock = i0 >> 5, qbase = (i0 & 31) >> 3;
    u16* base = WhTf + ((size_t)(hd * 4 + nt) * JW + jblock) * 512 + dc0 * 8;
    #pragma unroll
    for (int jh = 0; jh < 2; ++jh) {
      const int i = jh * 8;
      union { unsigned u[4]; int4 v; } pk;
      pk.u[0] = cvt2(pA[i + 0][d], pA[i + 1][d]);
      pk.u[1] = cvt2(pA[i + 2][d], pA[i + 3][d]);
      pk.u[2] = cvt2(pA[i + 4][d], pA[i + 5][d]);
      pk.u[3] = cvt2(pA[i + 6][d], pA[i + 7][d]);
      *(int4*)(base + (qbase + jh) * 128) = pk.v;
    }
  }
}

// ---------------------------------------------------------------------------
// K2: [A-rows -> LDS bitmask prologue, coalesced] + masked softmax + PV +
// fused projection. Block 1024 = 16 waves (hd = wv&3, jc = wv>>2).
// Hot loop: factored exp — P = mask * (s1+s2>=0 ? exp(s1)*exp(s2)
//                                              : exp(.2 s1)*exp(.2 s2));
// all transcendentals hoisted out of the O(L^2) loop.
// ---------------------------------------------------------------------------
__global__ __launch_bounds__(1024) void k2_attn(
    const int* __restrict__ A, const u16* __restrict__ WhTf,
    const float* __restrict__ s1g, const float2* __restrict__ bdg,
    const float* __restrict__ out_w, const float* __restrict__ out_b,
    float* __restrict__ out)
{
  const int i0 = blockIdx.x * 16;
  const int t = threadIdx.x;
  const int wv = t >> 6, lane = t & 63, q = lane >> 4, c0 = lane & 15;
  const int hd = wv & 3, jc = wv >> 2;
  int rowm[4], colm[4];
  mfma_cdmap(lane, rowm, colm);

  __shared__ float pA[NH][16][HD + 4];
  __shared__ float pB[NH][16][HD + 4];
  __shared__ float dden[NH][4][16];
  __shared__ float rcpS[NH][16];
  __shared__ u16  CnL[16][DOUT + 8];
  __shared__ unsigned AbitL[16][JW + 2];   // row-stride 130 -> varied banks

  {  // prologue: pack this block's 16 A-rows -> bitmask (coalesced reads)
    const int row = t >> 6, ln = t & 63;
    const int* Ar = A + (size_t)(i0 + row) * L_;
    #pragma unroll
    for (int wsel = 0; wsel < 2; ++wsel) {
      const int wI = ln * 2 + wsel;
      const int* p = Ar + wI * 32;
      unsigned bits = 0u;
      #pragma unroll
      for (int wd = 0; wd < 8; ++wd) {
        int4 v = *(const int4*)(p + wd * 4);
        bits |= (v.x > 0 ? 1u : 0u) << (wd * 4 + 0);
        bits |= (v.y > 0 ? 1u : 0u) << (wd * 4 + 1);
        bits |= (v.z > 0 ? 1u : 0u) << (wd * 4 + 2);
        bits |= (v.w > 0 ? 1u : 0u) << (wd * 4 + 3);
      }
      AbitL[row][wI] = bits;
    }
  }
  __syncthreads();

  const float s1v = s1g[hd * L_ + i0 + c0];
  const float av = __expf(s1v);          // exp(s1)
  const float cv = __expf(0.2f * s1v);   // exp(0.2*s1)
  const float th = __expf(-s1v);         // b >= th  <=>  s1+s2 >= 0
  const float2* bdh = bdg + (size_t)hd * L_;
  const u16* Wc = WhTf + (size_t)(hd * 4) * JW * 512 + (size_t)(jc * 32) * 512 + lane * 8;

  floatx4 acc[4] = {};
  float dpart = 0.f;
  const int jbase = jc * 1024;

  for (int kt = 0; kt < 32; ++kt) {
    const int kb = jbase + kt * 32 + q * 8;
    float4 v0 = *(const float4*)(bdh + kb);        // (b,d) for j: kb, kb+1
    float4 v1 = *(const float4*)(bdh + kb + 2);
    float4 v2 = *(const float4*)(bdh + kb + 4);
    float4 v3 = *(const float4*)(bdh + kb + 6);
    const float bb[8] = {v0.x, v0.z, v1.x, v1.z, v2.x, v2.z, v3.x, v3.z};
    const float dd[8] = {v0.y, v0.w, v1.y, v1.w, v2.y, v2.w, v3.y, v3.w};
    const unsigned mbits = (AbitL[c0][jc * 32 + kt] >> (q * 8)) & 0xffu;
    float ex[8];
    #pragma unroll
    for (int jj = 0; jj < 8; ++jj) {
      float p = (bb[jj] >= th) ? (av * bb[jj]) : (cv * dd[jj]);
      ex[jj] = ((mbits >> jj) & 1u) ? p : 0.f;      // mask = (A > 0)
      dpart += ex[jj];
    }
    union { unsigned u[4]; short8 s; } pf;          // P A-frag [m=c0][k=j]
    pf.u[0] = cvt2(ex[0], ex[1]); pf.u[1] = cvt2(ex[2], ex[3]);
    pf.u[2] = cvt2(ex[4], ex[5]); pf.u[3] = cvt2(ex[6], ex[7]);
    #pragma unroll
    for (int nt = 0; nt < 4; ++nt) {                // coalesced 1KB chunk loads
      short8 bfr = *(const short8*)(Wc + ((size_t)nt * JW + kt) * 512);
      acc[nt] = __builtin_amdgcn_mfma_f32_16x16x32_bf16(pf.s, bfr, acc[nt], 0, 0, 0);
    }
  }

  // partial denom of row c0 over this j-chunk
  dpart += __shfl_xor(dpart, 16, 64);
  dpart += __shfl_xor(dpart, 32, 64);
  if (lane < 16) dden[hd][jc][lane] = dpart;

  auto writeT = [&](float (*P)[HD + 4]) {
    #pragma unroll
    for (int nt = 0; nt < 4; ++nt)
      #pragma unroll
      for (int r = 0; r < 4; ++r)
        P[rowm[r]][nt * 16 + colm[r]] = acc[nt][r];
  };
  auto addB2A = [&]() {
    const int h2 = t >> 8, rem = t & 255, row = rem >> 4, d4 = (rem & 15) * 4;
    float4* a = (float4*)&pA[h2][row][d4];
    float4 bv = *(float4*)&pB[h2][row][d4];
    float4 av2 = *a;
    av2.x += bv.x; av2.y += bv.y; av2.z += bv.z; av2.w += bv.w;
    *a = av2;
  };

  if (jc == 0) writeT(pA[hd]);
  if (jc == 1) writeT(pB[hd]);
  __syncthreads();
  if (t < 64) {
    const int hh = t >> 4, r = t & 15;
    float den = dden[hh][0][r] + dden[hh][1][r] + dden[hh][2][r] + dden[hh][3][r];
    rcpS[hh][r] = (den > 0.f) ? (1.f / den) : 0.f;  // empty row -> out = bias
  }
  addB2A();
  __syncthreads();
  if (jc == 2) writeT(pB[hd]);
  __syncthreads();
  addB2A();
  __syncthreads();
  if (jc == 3) writeT(pB[hd]);
  __syncthreads();
  addB2A();
  __syncthreads();

  {  // Cn (bf16)
    const int row = t >> 6, c4 = (t & 63) * 4;
    #pragma unroll
    for (int x = 0; x < 4; ++x) {
      const int col = c4 + x;
      const int hh = col >> 6, d = col & 63;
      CnL[row][col] = f2bf(pA[hh][row][d] * rcpS[hh][row]);
    }
  }
  __syncthreads();

  if (wv < 4) {  // projection: Out2(16x256) = Cn @ out_w.T
    const int cg = wv;
    floatx4 o[4] = {};
    #pragma unroll
    for (int kt = 0; kt < DOUT / 32; ++kt) {
      const int kb2 = kt * 32 + q * 8;
      short8 afr = *(const short8*)(&CnL[c0][kb2]);
      #pragma unroll
      for (int nt = 0; nt < 4; ++nt) {
        const int col = cg * 64 + nt * 16 + c0;
        short8 bfo = pack8(out_w + (size_t)col * DOUT + kb2);
        o[nt] = __builtin_amdgcn_mfma_f32_16x16x32_bf16(afr, bfo, o[nt], 0, 0, 0);
      }
    }
    #pragma unroll
    for (int nt = 0; nt < 4; ++nt)
      #pragma unroll
      for (int r = 0; r < 4; ++r) {
        const int col = cg * 64 + nt * 16 + colm[r];
        out[(size_t)(i0 + rowm[r]) * DOUT + col] = o[nt][r] + out_b[col];
      }
  }
}

// ---------------------------------------------------------------------------
extern "C" void kernel_launch(void* const* d_in, const int* in_sizes, int n_in,
                              void* d_out, int out_size, void* d_ws, size_t ws_size,
                              hipStream_t stream) {
  const float* h     = (const float*)d_in[0];   // (4096, 512) fp32
  const int*   A     = (const int*)d_in[1];     // (4096, 4096) int32
  const float* W     = (const float*)d_in[2];   // (256, 512) fp32
  const float* attn  = (const float*)d_in[3];   // (4, 128) fp32
  const float* out_w = (const float*)d_in[4];   // (256, 256) fp32
  const float* out_b = (const float*)d_in[5];   // (256,) fp32
  float* outp = (float*)d_out;                  // (4096, 256) fp32

  // ws: WhTf bf16 (2 MB) | s1 f32 (64 KB) | bd float2 (128 KB)
  u16*    WhTf = (u16*)d_ws;
  float*  s1g  = (float*)((char*)d_ws + (size_t)DOUT * L_ * 2);
  float2* bdg  = (float2*)((char*)d_ws + (size_t)DOUT * L_ * 2 + (size_t)NH * L_ * 4);
  // Wf lives in d_out (k0b -> k1 -> k2 serialize; k2 overwrites d_out last)
  u16* Wf = (u16*)d_out;

  hipLaunchKernelGGL(k0b_wf, dim3(16), dim3(256), 0, stream, W, Wf);
  hipLaunchKernelGGL(k1_wh, dim3(L_ / 16), dim3(1024), 0, stream,
                     h, Wf, attn, WhTf, s1g, bdg);
  hipLaunchKernelGGL(k2_attn, dim3(L_ / 16), dim3(1024), 0, stream,
                     A, WhTf, s1g, bdg, out_w, out_b, outp);
}

// Round 2
// 161.828 us; speedup vs baseline: 1.0105x; 1.0105x over previous
//
#include <hip/hip_runtime.h>
#include <hip/hip_bf16.h>

#define L_    4096
#define DIN   512
#define DOUT  256
#define NH    4
#define HD    64
#define JW    128                      // L_/32 j-words per row

typedef unsigned short u16;
typedef __attribute__((ext_vector_type(8))) short short8;   // 8 x bf16
typedef __attribute__((ext_vector_type(4))) float floatx4;  // MFMA C/D frag

__device__ __forceinline__ float bf2f(u16 u) {
  union { unsigned u32; float f; } v; v.u32 = ((unsigned)u) << 16; return v.f;
}
__device__ __forceinline__ u16 f2bf(float f) {  // RNE
  union { float f; unsigned u; } v; v.f = f;
  unsigned r = v.u + 0x7fff + ((v.u >> 16) & 1);
  return (u16)(r >> 16);
}
__device__ __forceinline__ unsigned cvt2(float a, float b) {  // HW pack fp32x2->bf16x2
  __hip_bfloat162 v = __float22bfloat162_rn(make_float2(a, b));
  return *reinterpret_cast<unsigned*>(&v);
}
__device__ __forceinline__ short8 pack8(const float* __restrict__ p) {
  float4 a = *(const float4*)p, b = *(const float4*)(p + 4);
  union { unsigned u[4]; short8 s; } r;
  r.u[0] = cvt2(a.x, a.y); r.u[1] = cvt2(a.z, a.w);
  r.u[2] = cvt2(b.x, b.y); r.u[3] = cvt2(b.z, b.w);
  return r.s;
}

// C/D map discovery (r10-verified contract); layout-map-free probes.
__device__ __forceinline__ void mfma_cdmap(int lane, int* rowm, int* colm) {
  const int c0 = lane & 15;
  union { u16 u[8]; short8 s; } a1, b1, a2, b2;
  const u16 one = f2bf(1.f), cid = f2bf((float)c0);
  #pragma unroll
  for (int j = 0; j < 8; ++j) { a1.u[j] = cid; b1.u[j] = one; a2.u[j] = one; b2.u[j] = cid; }
  floatx4 z = {0.f, 0.f, 0.f, 0.f};
  floatx4 dr = __builtin_amdgcn_mfma_f32_16x16x32_bf16(a1.s, b1.s, z, 0, 0, 0);
  floatx4 dc = __builtin_amdgcn_mfma_f32_16x16x32_bf16(a2.s, b2.s, z, 0, 0, 0);
  #pragma unroll
  for (int r = 0; r < 4; ++r) {
    rowm[r] = (int)(dr[r] * 0.03125f + 0.5f);
    colm[r] = (int)(dc[r] * 0.03125f + 0.5f);
  }
}

// ---------------------------------------------------------------------------
// k0b: W (fp32 256x512) -> Wf (bf16, k1-fragment chunk order, 256 KB in d_out).
// ---------------------------------------------------------------------------
__global__ __launch_bounds__(256) void k0b_wf(const float* __restrict__ W,
                                              u16* __restrict__ Wf) {
  const int g = blockIdx.x * 256 + threadIdx.x;   // 4096 threads
  const int col = g >> 4, kblock = g & 15;
  const int cg = col >> 6, nt = (col >> 4) & 3, c0 = col & 15;
  const float* src = W + (size_t)col * DIN + kblock * 32;
  u16* dst = Wf + ((size_t)(cg * 4 + nt) * 16 + kblock) * 512 + c0 * 8;
  #pragma unroll
  for (int q = 0; q < 4; ++q) {
    short8 v = pack8(src + q * 8);
    *(short8*)(dst + q * 128) = v;     // (q*16+c0)*8 = q*128 + c0*8
  }
}

// ---------------------------------------------------------------------------
// K1: Wh = h @ W.T. Block 1024 = 16 waves (cg = wv&3, kc = wv>>2).
// (r13-verified) h staged to LDS bf16; W coalesced from Wf; phased 2-plane
// reduction. Outputs s1 fp32 + bd=(exp(s2),exp(.2*s2)) float2 + WhTf (bf16).
// ---------------------------------------------------------------------------
__global__ __launch_bounds__(1024) void k1_wh(
    const float* __restrict__ h, const u16* __restrict__ Wf,
    const float* __restrict__ attn,
    u16* __restrict__ WhTf, float* __restrict__ s1g, float2* __restrict__ bdg)
{
  const int i0 = blockIdx.x * 16;
  const int t = threadIdx.x;
  const int wv = t >> 6, lane = t & 63, q = lane >> 4, c0 = lane & 15;
  const int cg = wv & 3, kc = wv >> 2;
  int rowm[4], colm[4];
  mfma_cdmap(lane, rowm, colm);

  __shared__ u16  hT[16][DIN + 8];
  __shared__ float pA[16][DOUT + 8];
  __shared__ float pB[16][DOUT + 8];
  __shared__ float attnL[NH * 128];

  if (t < 512) attnL[t] = attn[t];
  {  // stage h-tile coalesced
    const int row = t >> 6, c8 = (t & 63) * 8;
    const float* hp = h + (size_t)(i0 + row) * DIN + c8;
    float4 a = *(const float4*)hp;
    float4 b = *(const float4*)(hp + 4);
    union { unsigned u[4]; int4 v; } pk;
    pk.u[0] = cvt2(a.x, a.y); pk.u[1] = cvt2(a.z, a.w);
    pk.u[2] = cvt2(b.x, b.y); pk.u[3] = cvt2(b.z, b.w);
    *(int4*)&hT[row][c8] = pk.v;
  }
  __syncthreads();

  floatx4 acc[4] = {};
  #pragma unroll
  for (int ktl = 0; ktl < 4; ++ktl) {
    const int kb = kc * 128 + ktl * 32 + q * 8;
    short8 af = *(const short8*)&hT[c0][kb];        // A[m=c0][k]
    #pragma unroll
    for (int nt = 0; nt < 4; ++nt) {
      short8 bf = *(const short8*)(Wf + ((size_t)(cg * 4 + nt) * 16 + kc * 4 + ktl) * 512 + lane * 8);
      acc[nt] = __builtin_amdgcn_mfma_f32_16x16x32_bf16(af, bf, acc[nt], 0, 0, 0);
    }
  }

  auto writeT = [&](float (*P)[DOUT + 8]) {
    #pragma unroll
    for (int nt = 0; nt < 4; ++nt)
      #pragma unroll
      for (int r = 0; r < 4; ++r)
        P[rowm[r]][cg * 64 + nt * 16 + colm[r]] = acc[nt][r];
  };
  auto addB2A = [&]() {
    const int row = t >> 6, c4 = (t & 63) * 4;
    float4* a = (float4*)&pA[row][c4];
    float4 bv = *(float4*)&pB[row][c4];
    float4 av = *a;
    av.x += bv.x; av.y += bv.y; av.z += bv.z; av.w += bv.w;
    *a = av;
  };

  if (kc == 0) writeT(pA);
  if (kc == 1) writeT(pB);
  __syncthreads();
  addB2A();
  __syncthreads();
  if (kc == 2) writeT(pB);
  __syncthreads();
  addB2A();
  __syncthreads();
  if (kc == 3) writeT(pB);
  __syncthreads();
  addB2A();
  __syncthreads();

  if (t < 64) {  // s1 + factored-exp pair for s2
    const int r = t & 15, hh = t >> 4;
    float s1 = 0.f, s2 = 0.f;
    for (int d = 0; d < HD; ++d) {
      float v = pA[r][hh * 64 + d];
      s1 += v * attnL[hh * 128 + d];
      s2 += v * attnL[hh * 128 + 64 + d];
    }
    s1g[hh * L_ + i0 + r] = s1;
    bdg[hh * L_ + i0 + r] = make_float2(__expf(s2), __expf(0.2f * s2));
  }

  if (t < 256) {  // WhTf store: thread t = d; two 16B writes
    const int d = t;
    const int hd = d >> 6, nt = (d >> 4) & 3, dc0 = d & 15;
    const int jblock = i0 >> 5, qbase = (i0 & 31) >> 3;
    u16* base = WhTf + ((size_t)(hd * 4 + nt) * JW + jblock) * 512 + dc0 * 8;
    #pragma unroll
    for (int jh = 0; jh < 2; ++jh) {
      const int i = jh * 8;
      union { unsigned u[4]; int4 v; } pk;
      pk.u[0] = cvt2(pA[i + 0][d], pA[i + 1][d]);
      pk.u[1] = cvt2(pA[i + 2][d], pA[i + 3][d]);
      pk.u[2] = cvt2(pA[i + 4][d], pA[i + 5][d]);
      pk.u[3] = cvt2(pA[i + 6][d], pA[i + 7][d]);
      *(int4*)(base + (qbase + jh) * 128) = pk.v;
    }
  }
}

// ---------------------------------------------------------------------------
// K2: masked softmax + PV + fused projection. Block 1024 = 16 waves
// (hd = wv&3, jc = wv>>2). Changes this round:
//  - hot loop is 1-deep software-pipelined (Wc x4 short8, bd x4 float4, mask
//    word) with manual 2x unroll + named A/B buffers (no runtime vec-indexing)
//  - A bitmask pack split into 4 chunks of 8 kt; chunk c+1's global loads
//    interleave one int4 per unrolled iteration inside chunk c's loop
//    (vmcnt is FIFO: bulk-issuing them before the loop would stall the
//    first prefetched-Wc wait until they retire).
// ---------------------------------------------------------------------------
__global__ __launch_bounds__(1024) void k2_attn(
    const int* __restrict__ A, const u16* __restrict__ WhTf,
    const float* __restrict__ s1g, const float2* __restrict__ bdg,
    const float* __restrict__ out_w, const float* __restrict__ out_b,
    float* __restrict__ out)
{
  const int i0 = blockIdx.x * 16;
  const int t = threadIdx.x;
  const int wv = t >> 6, lane = t & 63, q = lane >> 4, c0 = lane & 15;
  const int hd = wv & 3, jc = wv >> 2;
  int rowm[4], colm[4];
  mfma_cdmap(lane, rowm, colm);

  __shared__ float pA[NH][16][HD + 4];
  __shared__ float pB[NH][16][HD + 4];
  __shared__ float dden[NH][4][16];
  __shared__ float rcpS[NH][16];
  __shared__ u16  CnL[16][DOUT + 8];
  __shared__ u16  Ab16[16][2 * JW + 4];   // bitmask, 16-bit halves; stride 260

  // A-pack thread mapping: 1024 half-words per 8-kt chunk, one per thread.
  const int arow = t >> 6, aidx = t & 63;
  const int ajc = aidx >> 4, arest = aidx & 15, awo = arest >> 1, ahalf = arest & 1;
  const int* Abase = A + (size_t)(i0 + arow) * L_;
  auto apack_src = [&](int chunk) -> const int* {
    const int wI = ajc * 32 + chunk * 8 + awo;
    return Abase + wI * 32 + ahalf * 16;
  };
  auto astore = [&](int chunk, const int4* v) {
    unsigned bits = 0u;
    #pragma unroll
    for (int w = 0; w < 4; ++w) {
      bits |= (v[w].x > 0 ? 1u : 0u) << (w * 4 + 0);
      bits |= (v[w].y > 0 ? 1u : 0u) << (w * 4 + 1);
      bits |= (v[w].z > 0 ? 1u : 0u) << (w * 4 + 2);
      bits |= (v[w].w > 0 ? 1u : 0u) << (w * 4 + 3);
    }
    const int wI = ajc * 32 + chunk * 8 + awo;
    Ab16[arow][wI * 2 + ahalf] = (u16)bits;
  };

  {  // chunk 0: serial (only ~3 us exposed; chunks 1-3 hide under compute)
    const int* s = apack_src(0);
    int4 v0[4];
    #pragma unroll
    for (int w = 0; w < 4; ++w) v0[w] = *(const int4*)(s + w * 4);
    astore(0, v0);
  }
  __syncthreads();

  const float s1v = s1g[hd * L_ + i0 + c0];
  const float av = __expf(s1v);          // exp(s1)
  const float cv = __expf(0.2f * s1v);   // exp(0.2*s1)
  const float th = __expf(-s1v);         // b >= th  <=>  s1+s2 >= 0
  const float2* bdh = bdg + (size_t)hd * L_;
  const u16* Wc = WhTf + (size_t)(hd * 4) * JW * 512 + (size_t)(jc * 32) * 512 + lane * 8;
  const int jbase = jc * 1024;

  floatx4 acc[4] = {};
  float dpart = 0.f;

  auto loadW = [&](int kt, short8* w) {
    #pragma unroll
    for (int nt = 0; nt < 4; ++nt)
      w[nt] = *(const short8*)(Wc + ((size_t)nt * JW + kt) * 512);
  };
  auto loadV = [&](int kt, float4* v) {
    const float2* p = bdh + jbase + kt * 32 + q * 8;
    v[0] = *(const float4*)p;       v[1] = *(const float4*)(p + 2);
    v[2] = *(const float4*)(p + 4); v[3] = *(const float4*)(p + 6);
  };
  auto bits16 = [&](int kt) -> unsigned {
    return *(const unsigned*)&Ab16[c0][(jc * 32 + kt) * 2];
  };
  auto body = [&](const short8* w, const float4* v, unsigned wbits) {
    const unsigned mb = (wbits >> (q * 8)) & 0xffu;
    const float bb[8] = {v[0].x, v[0].z, v[1].x, v[1].z, v[2].x, v[2].z, v[3].x, v[3].z};
    const float dd[8] = {v[0].y, v[0].w, v[1].y, v[1].w, v[2].y, v[2].w, v[3].y, v[3].w};
    float ex[8];
    #pragma unroll
    for (int jj = 0; jj < 8; ++jj) {
      float p = (bb[jj] >= th) ? (av * bb[jj]) : (cv * dd[jj]);
      ex[jj] = ((mb >> jj) & 1u) ? p : 0.f;
      dpart += ex[jj];
    }
    union { unsigned u[4]; short8 s; } pf;          // P A-frag [m=c0][k=j]
    pf.u[0] = cvt2(ex[0], ex[1]); pf.u[1] = cvt2(ex[2], ex[3]);
    pf.u[2] = cvt2(ex[4], ex[5]); pf.u[3] = cvt2(ex[6], ex[7]);
    #pragma unroll
    for (int nt = 0; nt < 4; ++nt)
      acc[nt] = __builtin_amdgcn_mfma_f32_16x16x32_bf16(pf.s, w[nt], acc[nt], 0, 0, 0);
  };
  // 8 kt, 1-deep pipeline, 2x unroll (named bufs: no runtime vec-indexing).
  auto run8 = [&](int base, const int* Apre, int4* pre) {
    short8 wA[4], wB[4];
    float4 vA[4], vB[4];
    unsigned aA, aB;
    loadW(base, wA); loadV(base, vA); aA = bits16(base);
    #pragma unroll
    for (int kk = 0; kk < 4; ++kk) {
      const int kt = base + kk * 2;
      loadW(kt + 1, wB); loadV(kt + 1, vB); aB = bits16(kt + 1);
      if (Apre) pre[kk] = *(const int4*)(Apre + kk * 4);   // A-chunk prefetch
      body(wA, vA, aA);
      if (kk < 3) { loadW(kt + 2, wA); loadV(kt + 2, vA); aA = bits16(kt + 2); }
      body(wB, vB, aB);
    }
  };

  int4 pre[4];
  run8(0, apack_src(1), pre);
  astore(1, pre);
  __syncthreads();
  run8(8, apack_src(2), pre);
  astore(2, pre);
  __syncthreads();
  run8(16, apack_src(3), pre);
  astore(3, pre);
  __syncthreads();
  run8(24, nullptr, pre);

  // partial denom of row c0 over this j-chunk
  dpart += __shfl_xor(dpart, 16, 64);
  dpart += __shfl_xor(dpart, 32, 64);
  if (lane < 16) dden[hd][jc][lane] = dpart;

  auto writeT = [&](float (*P)[HD + 4]) {
    #pragma unroll
    for (int nt = 0; nt < 4; ++nt)
      #pragma unroll
      for (int r = 0; r < 4; ++r)
        P[rowm[r]][nt * 16 + colm[r]] = acc[nt][r];
  };
  auto addB2A = [&]() {
    const int h2 = t >> 8, rem = t & 255, row = rem >> 4, d4 = (rem & 15) * 4;
    float4* a = (float4*)&pA[h2][row][d4];
    float4 bv = *(float4*)&pB[h2][row][d4];
    float4 av2 = *a;
    av2.x += bv.x; av2.y += bv.y; av2.z += bv.z; av2.w += bv.w;
    *a = av2;
  };

  if (jc == 0) writeT(pA[hd]);
  if (jc == 1) writeT(pB[hd]);
  __syncthreads();
  if (t < 64) {
    const int hh = t >> 4, r = t & 15;
    float den = dden[hh][0][r] + dden[hh][1][r] + dden[hh][2][r] + dden[hh][3][r];
    rcpS[hh][r] = (den > 0.f) ? (1.f / den) : 0.f;  // empty row -> out = bias
  }
  addB2A();
  __syncthreads();
  if (jc == 2) writeT(pB[hd]);
  __syncthreads();
  addB2A();
  __syncthreads();
  if (jc == 3) writeT(pB[hd]);
  __syncthreads();
  addB2A();
  __syncthreads();

  {  // Cn (bf16)
    const int row = t >> 6, c4 = (t & 63) * 4;
    #pragma unroll
    for (int x = 0; x < 4; ++x) {
      const int col = c4 + x;
      const int hh = col >> 6, d = col & 63;
      CnL[row][col] = f2bf(pA[hh][row][d] * rcpS[hh][row]);
    }
  }
  __syncthreads();

  if (wv < 4) {  // projection: Out2(16x256) = Cn @ out_w.T
    const int cg = wv;
    floatx4 o[4] = {};
    #pragma unroll
    for (int kt = 0; kt < DOUT / 32; ++kt) {
      const int kb2 = kt * 32 + q * 8;
      short8 afr = *(const short8*)(&CnL[c0][kb2]);
      #pragma unroll
      for (int nt = 0; nt < 4; ++nt) {
        const int col = cg * 64 + nt * 16 + c0;
        short8 bfo = pack8(out_w + (size_t)col * DOUT + kb2);
        o[nt] = __builtin_amdgcn_mfma_f32_16x16x32_bf16(afr, bfo, o[nt], 0, 0, 0);
      }
    }
    #pragma unroll
    for (int nt = 0; nt < 4; ++nt)
      #pragma unroll
      for (int r = 0; r < 4; ++r) {
        const int col = cg * 64 + nt * 16 + colm[r];
        out[(size_t)(i0 + rowm[r]) * DOUT + col] = o[nt][r] + out_b[col];
      }
  }
}

// ---------------------------------------------------------------------------
extern "C" void kernel_launch(void* const* d_in, const int* in_sizes, int n_in,
                              void* d_out, int out_size, void* d_ws, size_t ws_size,
                              hipStream_t stream) {
  const float* h     = (const float*)d_in[0];   // (4096, 512) fp32
  const int*   A     = (const int*)d_in[1];     // (4096, 4096) int32
  const float* W     = (const float*)d_in[2];   // (256, 512) fp32
  const float* attn  = (const float*)d_in[3];   // (4, 128) fp32
  const float* out_w = (const float*)d_in[4];   // (256, 256) fp32
  const float* out_b = (const float*)d_in[5];   // (256,) fp32
  float* outp = (float*)d_out;                  // (4096, 256) fp32

  // ws: WhTf bf16 (2 MB) | s1 f32 (64 KB) | bd float2 (128 KB)
  u16*    WhTf = (u16*)d_ws;
  float*  s1g  = (float*)((char*)d_ws + (size_t)DOUT * L_ * 2);
  float2* bdg  = (float2*)((char*)d_ws + (size_t)DOUT * L_ * 2 + (size_t)NH * L_ * 4);
  // Wf lives in d_out (k0b -> k1 -> k2 serialize; k2 overwrites d_out last)
  u16* Wf = (u16*)d_out;

  hipLaunchKernelGGL(k0b_wf, dim3(16), dim3(256), 0, stream, W, Wf);
  hipLaunchKernelGGL(k1_wh, dim3(L_ / 16), dim3(1024), 0, stream,
                     h, Wf, attn, WhTf, s1g, bdg);
  hipLaunchKernelGGL(k2_attn, dim3(L_ / 16), dim3(1024), 0, stream,
                     A, WhTf, s1g, bdg, out_w, out_b, outp);
}

// Round 3
// 156.325 us; speedup vs baseline: 1.0461x; 1.0352x over previous
//
#include <hip/hip_runtime.h>
#include <hip/hip_bf16.h>

#define L_    4096
#define DIN   512
#define DOUT  256
#define NH    4
#define HD    64
#define JW    128                      // L_/32 j-words per row

typedef unsigned short u16;
typedef __attribute__((ext_vector_type(8))) short short8;   // 8 x bf16
typedef __attribute__((ext_vector_type(4))) float floatx4;  // MFMA C/D frag

__device__ __forceinline__ float bf2f(u16 u) {
  union { unsigned u32; float f; } v; v.u32 = ((unsigned)u) << 16; return v.f;
}
__device__ __forceinline__ u16 f2bf(float f) {  // RNE
  union { float f; unsigned u; } v; v.f = f;
  unsigned r = v.u + 0x7fff + ((v.u >> 16) & 1);
  return (u16)(r >> 16);
}
__device__ __forceinline__ unsigned cvt2(float a, float b) {  // HW pack fp32x2->bf16x2
  __hip_bfloat162 v = __float22bfloat162_rn(make_float2(a, b));
  return *reinterpret_cast<unsigned*>(&v);
}
__device__ __forceinline__ short8 pack8(const float* __restrict__ p) {
  float4 a = *(const float4*)p, b = *(const float4*)(p + 4);
  union { unsigned u[4]; short8 s; } r;
  r.u[0] = cvt2(a.x, a.y); r.u[1] = cvt2(a.z, a.w);
  r.u[2] = cvt2(b.x, b.y); r.u[3] = cvt2(b.z, b.w);
  return r.s;
}

// C/D map discovery (r10-verified contract); layout-map-free probes.
__device__ __forceinline__ void mfma_cdmap(int lane, int* rowm, int* colm) {
  const int c0 = lane & 15;
  union { u16 u[8]; short8 s; } a1, b1, a2, b2;
  const u16 one = f2bf(1.f), cid = f2bf((float)c0);
  #pragma unroll
  for (int j = 0; j < 8; ++j) { a1.u[j] = cid; b1.u[j] = one; a2.u[j] = one; b2.u[j] = cid; }
  floatx4 z = {0.f, 0.f, 0.f, 0.f};
  floatx4 dr = __builtin_amdgcn_mfma_f32_16x16x32_bf16(a1.s, b1.s, z, 0, 0, 0);
  floatx4 dc = __builtin_amdgcn_mfma_f32_16x16x32_bf16(a2.s, b2.s, z, 0, 0, 0);
  #pragma unroll
  for (int r = 0; r < 4; ++r) {
    rowm[r] = (int)(dr[r] * 0.03125f + 0.5f);
    colm[r] = (int)(dc[r] * 0.03125f + 0.5f);
  }
}

// ---------------------------------------------------------------------------
// k_ab: A (int32 4096x4096, 64 MB) -> Abits (u32 bitmask, 2 MB).
// Pure streaming at HBM BW. Wave-cooperative pack: lane l reads int4
// (4 ints -> 4 bits), nibble placed at ((l&7)*4), OR-combined across 8-lane
// groups via shfl_xor; lanes l%8==0 store the u32 word.
// ---------------------------------------------------------------------------
__global__ __launch_bounds__(256) void k_ab(const int* __restrict__ A,
                                            unsigned* __restrict__ Abits) {
  const int g = blockIdx.x * 256 + threadIdx.x;   // 524288 threads
  const int lane = threadIdx.x & 63;
  #pragma unroll
  for (int r = 0; r < 8; ++r) {
    const size_t gi = (size_t)r * 524288 + g;     // int4 index (gi % 8 == lane % 8)
    int4 v = *(const int4*)(A + gi * 4);
    unsigned nib = (v.x > 0 ? 1u : 0u) | (v.y > 0 ? 2u : 0u)
                 | (v.z > 0 ? 4u : 0u) | (v.w > 0 ? 8u : 0u);
    unsigned part = nib << ((lane & 7) * 4);
    part |= __shfl_xor(part, 1, 64);
    part |= __shfl_xor(part, 2, 64);
    part |= __shfl_xor(part, 4, 64);
    if ((lane & 7) == 0) Abits[gi >> 3] = part;
  }
}

// ---------------------------------------------------------------------------
// k0b: W (fp32 256x512) -> Wf (bf16, k1-fragment chunk order, 256 KB in d_out).
// ---------------------------------------------------------------------------
__global__ __launch_bounds__(256) void k0b_wf(const float* __restrict__ W,
                                              u16* __restrict__ Wf) {
  const int g = blockIdx.x * 256 + threadIdx.x;   // 4096 threads
  const int col = g >> 4, kblock = g & 15;
  const int cg = col >> 6, nt = (col >> 4) & 3, c0 = col & 15;
  const float* src = W + (size_t)col * DIN + kblock * 32;
  u16* dst = Wf + ((size_t)(cg * 4 + nt) * 16 + kblock) * 512 + c0 * 8;
  #pragma unroll
  for (int q = 0; q < 4; ++q) {
    short8 v = pack8(src + q * 8);
    *(short8*)(dst + q * 128) = v;     // (q*16+c0)*8 = q*128 + c0*8
  }
}

// ---------------------------------------------------------------------------
// K1: Wh = h @ W.T. Block 1024 = 16 waves (cg = wv&3, kc = wv>>2).
// (r13-verified) h staged to LDS bf16; W coalesced from Wf; phased 2-plane
// reduction. Outputs s1 fp32 + bd=(exp(s2),exp(.2*s2)) float2 + WhTf (bf16).
// ---------------------------------------------------------------------------
__global__ __launch_bounds__(1024) void k1_wh(
    const float* __restrict__ h, const u16* __restrict__ Wf,
    const float* __restrict__ attn,
    u16* __restrict__ WhTf, float* __restrict__ s1g, float2* __restrict__ bdg)
{
  const int i0 = blockIdx.x * 16;
  const int t = threadIdx.x;
  const int wv = t >> 6, lane = t & 63, q = lane >> 4, c0 = lane & 15;
  const int cg = wv & 3, kc = wv >> 2;
  int rowm[4], colm[4];
  mfma_cdmap(lane, rowm, colm);

  __shared__ u16  hT[16][DIN + 8];
  __shared__ float pA[16][DOUT + 8];
  __shared__ float pB[16][DOUT + 8];
  __shared__ float attnL[NH * 128];

  if (t < 512) attnL[t] = attn[t];
  {  // stage h-tile coalesced
    const int row = t >> 6, c8 = (t & 63) * 8;
    const float* hp = h + (size_t)(i0 + row) * DIN + c8;
    float4 a = *(const float4*)hp;
    float4 b = *(const float4*)(hp + 4);
    union { unsigned u[4]; int4 v; } pk;
    pk.u[0] = cvt2(a.x, a.y); pk.u[1] = cvt2(a.z, a.w);
    pk.u[2] = cvt2(b.x, b.y); pk.u[3] = cvt2(b.z, b.w);
    *(int4*)&hT[row][c8] = pk.v;
  }
  __syncthreads();

  floatx4 acc[4] = {};
  #pragma unroll
  for (int ktl = 0; ktl < 4; ++ktl) {
    const int kb = kc * 128 + ktl * 32 + q * 8;
    short8 af = *(const short8*)&hT[c0][kb];        // A[m=c0][k]
    #pragma unroll
    for (int nt = 0; nt < 4; ++nt) {
      short8 bf = *(const short8*)(Wf + ((size_t)(cg * 4 + nt) * 16 + kc * 4 + ktl) * 512 + lane * 8);
      acc[nt] = __builtin_amdgcn_mfma_f32_16x16x32_bf16(af, bf, acc[nt], 0, 0, 0);
    }
  }

  auto writeT = [&](float (*P)[DOUT + 8]) {
    #pragma unroll
    for (int nt = 0; nt < 4; ++nt)
      #pragma unroll
      for (int r = 0; r < 4; ++r)
        P[rowm[r]][cg * 64 + nt * 16 + colm[r]] = acc[nt][r];
  };
  auto addB2A = [&]() {
    const int row = t >> 6, c4 = (t & 63) * 4;
    float4* a = (float4*)&pA[row][c4];
    float4 bv = *(float4*)&pB[row][c4];
    float4 av = *a;
    av.x += bv.x; av.y += bv.y; av.z += bv.z; av.w += bv.w;
    *a = av;
  };

  if (kc == 0) writeT(pA);
  if (kc == 1) writeT(pB);
  __syncthreads();
  addB2A();
  __syncthreads();
  if (kc == 2) writeT(pB);
  __syncthreads();
  addB2A();
  __syncthreads();
  if (kc == 3) writeT(pB);
  __syncthreads();
  addB2A();
  __syncthreads();

  if (t < 64) {  // s1 + factored-exp pair for s2
    const int r = t & 15, hh = t >> 4;
    float s1 = 0.f, s2 = 0.f;
    for (int d = 0; d < HD; ++d) {
      float v = pA[r][hh * 64 + d];
      s1 += v * attnL[hh * 128 + d];
      s2 += v * attnL[hh * 128 + 64 + d];
    }
    s1g[hh * L_ + i0 + r] = s1;
    bdg[hh * L_ + i0 + r] = make_float2(__expf(s2), __expf(0.2f * s2));
  }

  if (t < 256) {  // WhTf store: thread t = d; two 16B writes
    const int d = t;
    const int hd = d >> 6, nt = (d >> 4) & 3, dc0 = d & 15;
    const int jblock = i0 >> 5, qbase = (i0 & 31) >> 3;
    u16* base = WhTf + ((size_t)(hd * 4 + nt) * JW + jblock) * 512 + dc0 * 8;
    #pragma unroll
    for (int jh = 0; jh < 2; ++jh) {
      const int i = jh * 8;
      union { unsigned u[4]; int4 v; } pk;
      pk.u[0] = cvt2(pA[i + 0][d], pA[i + 1][d]);
      pk.u[1] = cvt2(pA[i + 2][d], pA[i + 3][d]);
      pk.u[2] = cvt2(pA[i + 4][d], pA[i + 5][d]);
      pk.u[3] = cvt2(pA[i + 6][d], pA[i + 7][d]);
      *(int4*)(base + (qbase + jh) * 128) = pk.v;
    }
  }
}

// ---------------------------------------------------------------------------
// K2: masked softmax + PV + fused projection. Block 1024 = 16 waves
// (hd = wv&3, jc = wv>>2). This round:
//  - A is PRE-PACKED by k_ab; prologue stages 8 KB of bitmask to LDS
//    (coalesced); hot loop has zero HBM traffic and no mid-loop barriers.
//  - hot loop: 2-kt software pipeline with NAMED buffers and softmax hoisted
//    to prefetch time (in-flight P state is a 4-VGPR frag, not 32 raw bd
//    floats). sched_barrier(0) fences pin issue-before-consume so the
//    scheduler cannot collapse the pipeline (R2 failure: VGPR=64 proved
//    loads were sunk to uses). All vmcnt waits become counted (8/12).
// ---------------------------------------------------------------------------
__global__ __launch_bounds__(1024) void k2_attn(
    const unsigned* __restrict__ Abits, const u16* __restrict__ WhTf,
    const float* __restrict__ s1g, const float2* __restrict__ bdg,
    const float* __restrict__ out_w, const float* __restrict__ out_b,
    float* __restrict__ out)
{
  const int i0 = blockIdx.x * 16;
  const int t = threadIdx.x;
  const int wv = t >> 6, lane = t & 63, q = lane >> 4, c0 = lane & 15;
  const int hd = wv & 3, jc = wv >> 2;

  __shared__ float pA[NH][16][HD + 4];
  __shared__ float pB[NH][16][HD + 4];
  __shared__ float dden[NH][4][16];
  __shared__ float rcpS[NH][16];
  __shared__ u16  CnL[16][DOUT + 8];
  __shared__ unsigned AbitL[16][JW + 2];   // row-stride 130 -> varied banks

  {  // prologue: stage this block's 16 rows of the bitmask (8 KB, coalesced)
    const int row = t >> 6, l = t & 63;
    uint2 w2 = *(const uint2*)&Abits[(size_t)(i0 + row) * JW + l * 2];
    AbitL[row][l * 2] = w2.x;
    AbitL[row][l * 2 + 1] = w2.y;
  }
  int rowm[4], colm[4];
  mfma_cdmap(lane, rowm, colm);
  __syncthreads();

  const float s1v = s1g[hd * L_ + i0 + c0];
  const float av = __expf(s1v);          // exp(s1)
  const float cv = __expf(0.2f * s1v);   // exp(0.2*s1)
  const float th = __expf(-s1v);         // b >= th  <=>  s1+s2 >= 0
  const float2* bdh = bdg + (size_t)hd * L_;
  const u16* Wc = WhTf + (size_t)(hd * 4) * JW * 512 + (size_t)(jc * 32) * 512 + lane * 8;
  const int jbase = jc * 1024;

  floatx4 acc[4] = {};
  float dpart = 0.f;

  union PF { unsigned u[4]; short8 s; };

  auto issueV = [&](int kt, float4* v) {
    const float2* p = bdh + jbase + kt * 32 + q * 8;
    v[0] = *(const float4*)p;       v[1] = *(const float4*)(p + 2);
    v[2] = *(const float4*)(p + 4); v[3] = *(const float4*)(p + 6);
  };
  auto issueW = [&](int kt, short8* w) {
    #pragma unroll
    for (int nt = 0; nt < 4; ++nt)
      w[nt] = *(const short8*)(Wc + ((size_t)nt * JW + kt) * 512);
  };
  auto sm8 = [&](const float4* v, int kt, PF& pf) {  // softmax -> bf16 A-frag
    const unsigned mb = (AbitL[c0][jc * 32 + kt] >> (q * 8)) & 0xffu;
    const float bb[8] = {v[0].x, v[0].z, v[1].x, v[1].z, v[2].x, v[2].z, v[3].x, v[3].z};
    const float dd[8] = {v[0].y, v[0].w, v[1].y, v[1].w, v[2].y, v[2].w, v[3].y, v[3].w};
    float ex[8];
    #pragma unroll
    for (int jj = 0; jj < 8; ++jj) {
      float p = (bb[jj] >= th) ? (av * bb[jj]) : (cv * dd[jj]);
      ex[jj] = ((mb >> jj) & 1u) ? p : 0.f;
      dpart += ex[jj];
    }
    pf.u[0] = cvt2(ex[0], ex[1]); pf.u[1] = cvt2(ex[2], ex[3]);
    pf.u[2] = cvt2(ex[4], ex[5]); pf.u[3] = cvt2(ex[6], ex[7]);
  };
  auto mfma4 = [&](PF& pf, const short8* w) {
    #pragma unroll
    for (int nt = 0; nt < 4; ++nt)
      acc[nt] = __builtin_amdgcn_mfma_f32_16x16x32_bf16(pf.s, w[nt], acc[nt], 0, 0, 0);
  };

  float4 vA[4], vB[4];
  short8 wA[4], wB[4];
  PF pfA, pfB;

  // prologue: fill both slots, pre-softmax slot A
  issueV(0, vA); issueW(0, wA);
  issueV(1, vB); issueW(1, wB);
  __builtin_amdgcn_sched_barrier(0);
  sm8(vA, 0, pfA);

  #pragma unroll 1
  for (int u = 0; u < 15; ++u) {
    const int kt = 2 * u;
    issueV(kt + 2, vA);                      // vA freed by sm8 last iter
    __builtin_amdgcn_sched_barrier(0);
    sm8(vB, kt + 1, pfB);                    // vB issued last iter (covered)
    mfma4(pfA, wA);                          // wA issued last iter (covered)
    __builtin_amdgcn_sched_barrier(0);
    issueW(kt + 2, wA);
    issueV(kt + 3, vB);
    __builtin_amdgcn_sched_barrier(0);
    mfma4(pfB, wB);                          // wB issued last iter (covered)
    __builtin_amdgcn_sched_barrier(0);
    issueW(kt + 3, wB);
    sm8(vA, kt + 2, pfA);                    // vA issued at loop top
    __builtin_amdgcn_sched_barrier(0);
  }
  // epilogue: pfA/wA hold kt=30, vB/wB hold kt=31
  mfma4(pfA, wA);
  sm8(vB, 31, pfB);
  mfma4(pfB, wB);

  // partial denom of row c0 over this j-chunk
  dpart += __shfl_xor(dpart, 16, 64);
  dpart += __shfl_xor(dpart, 32, 64);
  if (lane < 16) dden[hd][jc][lane] = dpart;

  auto writeT = [&](float (*P)[HD + 4]) {
    #pragma unroll
    for (int nt = 0; nt < 4; ++nt)
      #pragma unroll
      for (int r = 0; r < 4; ++r)
        P[rowm[r]][nt * 16 + colm[r]] = acc[nt][r];
  };
  auto addB2A = [&]() {
    const int h2 = t >> 8, rem = t & 255, row = rem >> 4, d4 = (rem & 15) * 4;
    float4* a = (float4*)&pA[h2][row][d4];
    float4 bv = *(float4*)&pB[h2][row][d4];
    float4 av2 = *a;
    av2.x += bv.x; av2.y += bv.y; av2.z += bv.z; av2.w += bv.w;
    *a = av2;
  };

  if (jc == 0) writeT(pA[hd]);
  if (jc == 1) writeT(pB[hd]);
  __syncthreads();
  if (t < 64) {
    const int hh = t >> 4, r = t & 15;
    float den = dden[hh][0][r] + dden[hh][1][r] + dden[hh][2][r] + dden[hh][3][r];
    rcpS[hh][r] = (den > 0.f) ? (1.f / den) : 0.f;  // empty row -> out = bias
  }
  addB2A();
  __syncthreads();
  if (jc == 2) writeT(pB[hd]);
  __syncthreads();
  addB2A();
  __syncthreads();
  if (jc == 3) writeT(pB[hd]);
  __syncthreads();
  addB2A();
  __syncthreads();

  {  // Cn (bf16)
    const int row = t >> 6, c4 = (t & 63) * 4;
    #pragma unroll
    for (int x = 0; x < 4; ++x) {
      const int col = c4 + x;
      const int hh = col >> 6, d = col & 63;
      CnL[row][col] = f2bf(pA[hh][row][d] * rcpS[hh][row]);
    }
  }
  __syncthreads();

  if (wv < 4) {  // projection: Out2(16x256) = Cn @ out_w.T
    const int cg = wv;
    floatx4 o[4] = {};
    #pragma unroll
    for (int kt = 0; kt < DOUT / 32; ++kt) {
      const int kb2 = kt * 32 + q * 8;
      short8 afr = *(const short8*)(&CnL[c0][kb2]);
      #pragma unroll
      for (int nt = 0; nt < 4; ++nt) {
        const int col = cg * 64 + nt * 16 + c0;
        short8 bfo = pack8(out_w + (size_t)col * DOUT + kb2);
        o[nt] = __builtin_amdgcn_mfma_f32_16x16x32_bf16(afr, bfo, o[nt], 0, 0, 0);
      }
    }
    #pragma unroll
    for (int nt = 0; nt < 4; ++nt)
      #pragma unroll
      for (int r = 0; r < 4; ++r) {
        const int col = cg * 64 + nt * 16 + colm[r];
        out[(size_t)(i0 + rowm[r]) * DOUT + col] = o[nt][r] + out_b[col];
      }
  }
}

// ---------------------------------------------------------------------------
extern "C" void kernel_launch(void* const* d_in, const int* in_sizes, int n_in,
                              void* d_out, int out_size, void* d_ws, size_t ws_size,
                              hipStream_t stream) {
  const float* h     = (const float*)d_in[0];   // (4096, 512) fp32
  const int*   A     = (const int*)d_in[1];     // (4096, 4096) int32
  const float* W     = (const float*)d_in[2];   // (256, 512) fp32
  const float* attn  = (const float*)d_in[3];   // (4, 128) fp32
  const float* out_w = (const float*)d_in[4];   // (256, 256) fp32
  const float* out_b = (const float*)d_in[5];   // (256,) fp32
  float* outp = (float*)d_out;                  // (4096, 256) fp32

  // ws: WhTf bf16 (2 MB) | s1 f32 (64 KB) | bd float2 (128 KB) | Abits (2 MB)
  const size_t WHTF_B = (size_t)DOUT * L_ * 2;          // 2097152
  const size_t S1_B   = (size_t)NH * L_ * 4;            // 65536
  const size_t BD_B   = (size_t)NH * L_ * 8;            // 131072
  const size_t AB_OFF = WHTF_B + S1_B + BD_B;           // 2293760
  u16*    WhTf = (u16*)d_ws;
  float*  s1g  = (float*)((char*)d_ws + WHTF_B);
  float2* bdg  = (float2*)((char*)d_ws + WHTF_B + S1_B);
  // Abits: prefer ws; fall back to the second 2 MB of d_out (disjoint from
  // Wf @ d_out[0..256KB]; k2 stages it to LDS in its prologue, long before
  // any co-resident block reaches the output write).
  unsigned* Abits = (ws_size >= AB_OFF + (size_t)L_ * JW * 4 )
                  ? (unsigned*)((char*)d_ws + AB_OFF)
                  : (unsigned*)((char*)d_out + 2097152);
  // Wf lives in d_out (k0b -> k1 -> k2 serialize; k2 overwrites d_out last)
  u16* Wf = (u16*)d_out;

  hipLaunchKernelGGL(k_ab, dim3(2048), dim3(256), 0, stream, A, Abits);
  hipLaunchKernelGGL(k0b_wf, dim3(16), dim3(256), 0, stream, W, Wf);
  hipLaunchKernelGGL(k1_wh, dim3(L_ / 16), dim3(1024), 0, stream,
                     h, Wf, attn, WhTf, s1g, bdg);
  hipLaunchKernelGGL(k2_attn, dim3(L_ / 16), dim3(1024), 0, stream,
                     Abits, WhTf, s1g, bdg, out_w, out_b, outp);
}